// Round 1
// baseline (92.306 us; speedup 1.0000x reference)
//
#include <hip/hip_runtime.h>

// PrRoIPool2D forward, MI355X. B=8, C=256, H=W=48, R=300, 7x7 bins, scale=1/16.
// R11: single fused kernel, NO workspace, NO prep launch.
//  - bounds (b, J0, I0, JROWS, NI4) recomputed redundantly per thread (~30 ops)
//  - hat-integral weights computed cooperatively by lanes 0..14 into a 396 B
//    LDS param block, overlapped with P1 global->LDS staging, merged into the
//    existing P1 barrier (no extra __syncthreads)
//  - P1 unit space compacted to 2*JROWS*7 (was fixed 322) -> single pass typical
// Phases: P1 stage patch [j][i][c8] -> PA row-sums rs[pw][j][c8] -> PB combine.
// LDS 26.2 KB -> 6 blocks/CU.

#define PH 7
#define PW 7
#define NBINS 49
#define SCALE 0.0625f
#define CH 256
#define FH 48
#define FW 48
#define RNUM 300
#define CB 8                 // channels per block
#define MAXJ 23              // max patch rows
#define ROWF 28              // max patch row width (floats)
// pbuf layout (LDS, 99 floats): [0+ph*6]: wy[7][6] | [42+pw*6]: wx[7][6]
// [84+ph]: bj (int, rel J0) | [91+pw]: bi (int, rel I0) | [98]: inv_area

__device__ __forceinline__ float hat_int(float x, float g) {
    float t = x - (g - 1.0f);
    if (t <= 0.0f) return 0.0f;
    if (t <= 1.0f) return 0.5f * t * t;
    if (t <= 2.0f) { float u = 2.0f - t; return 1.0f - 0.5f * u * u; }
    return 1.0f;
}

__global__ __launch_bounds__(256)
void prroi_fused(const float* __restrict__ feat,
                 const float* __restrict__ rois,
                 float* __restrict__ out) {
    const int cblk = blockIdx.x;        // 0..31
    const int r    = blockIdx.y;        // 0..299
    const int c0   = cblk * CB;
    const int tid  = threadIdx.x;

    __shared__ float patch[MAXJ * ROWF * CB];   // [j][i][c8] 20608 B
    __shared__ float rs[PW * MAXJ * CB];        // [pw][j][c8]  5152 B
    __shared__ float pbuf[99];                  // weights/offsets  396 B

    // ---- redundant per-thread ROI bounds (cheap, needed for P1 addressing) ----
    const float* roi = rois + r * 5;
    const float f0 = roi[0], f1 = roi[1], f2 = roi[2], f3 = roi[3], f4 = roi[4];
    const int   b  = (int)f0;
    const float x1 = f1 * SCALE, y1 = f2 * SCALE;
    const float x2 = f3 * SCALE, y2 = f4 * SCALE;
    const float ylo = fminf(y1, y2), yhi = fmaxf(y1, y2);
    const float xlo = fminf(x1, x2), xhi = fmaxf(x1, x2);
    const int j1 = min(FH - 1, (int)floorf(yhi) + 1);
    const int i1 = min(FW - 1, (int)floorf(xhi) + 1);
    const int J0 = min(max(0, (int)floorf(ylo) - 1), FH - 6);
    const int I0 = min(max(0, (int)floorf(xlo) - 1) & ~3, FW - 8);
    const int JROWS = min(FH - J0, max(j1 - J0 + 1, 6));        // 6..23
    int NI4 = min(((i1 - I0) >> 2) + 1, (FW - I0) >> 2);
    NI4 = max(NI4, 2);                                           // 2..7

    // ---- P1: stage patch rectangle, channel-fast, 4x4 register transpose ----
    // compact unit space: u = q*J7 + j*7 + i4, q in {0,1} (channel quads)
    const float* fb = feat + (size_t)(b * CH + c0) * FH * FW;
    const int J7 = JROWS * 7;
    for (int u = tid; u < 2 * J7; u += 256) {    // <= 322, 1 pass typical
        const int q  = (u >= J7) ? 1 : 0;
        const int rm = u - q * J7;
        const int j  = rm / 7;                    // const-divide -> magic mul
        const int i4 = rm - j * 7;
        if (i4 < NI4) {
            const int ig = I0 + 4 * i4;           // <= FW-4 by construction
            const float* src = fb + ((size_t)(4 * q) * FH + (J0 + j)) * FW + ig;
            const float4 v0  = *(const float4*)(src);
            const float4 v1v = *(const float4*)(src + FH * FW);
            const float4 v2v = *(const float4*)(src + 2 * FH * FW);
            const float4 v3v = *(const float4*)(src + 3 * FH * FW);
            float* dst = &patch[((size_t)j * ROWF + 4 * i4) * CB + 4 * q];
            *(float4*)(dst + 0 * CB) = make_float4(v0.x, v1v.x, v2v.x, v3v.x);
            *(float4*)(dst + 1 * CB) = make_float4(v0.y, v1v.y, v2v.y, v3v.y);
            *(float4*)(dst + 2 * CB) = make_float4(v0.z, v1v.z, v2v.z, v3v.z);
            *(float4*)(dst + 3 * CB) = make_float4(v0.w, v1v.w, v2v.w, v3v.w);
        }
    }

    // ---- cooperative weight computation, lanes 0..14 (overlaps P1 latency) ----
    // arithmetic forms identical to the old prep kernel (bit-stable vs R10)
    if (tid < PH) {                               // wy row weights for ph=tid
        const float roi_h = fmaxf(y2 - y1, 0.0f);
        const float bin_h = roi_h / (float)PH;
        const int ph = tid;
        const float ya = y1 + ph * bin_h, yb = ya + bin_h;
        const int base = min(max((int)floorf(ya) - 1, J0), J0 + JROWS - 6);
        pbuf[84 + ph] = __int_as_float(base - J0);
#pragma unroll
        for (int k = 0; k < 6; ++k) {
            const float g = (float)(base + k);
            pbuf[ph * 6 + k] = hat_int(yb, g) - hat_int(ya, g);
        }
    } else if (tid < PH + PW) {                   // wx col weights for pw=tid-7
        const float roi_w = fmaxf(x2 - x1, 0.0f);
        const float bin_w = roi_w / (float)PW;
        const int pw = tid - PH;
        const float xa = x1 + pw * bin_w, xb = xa + bin_w;
        const int base = min(max((int)floorf(xa) - 1, I0), I0 + 4 * NI4 - 6);
        pbuf[91 + pw] = __int_as_float(base - I0);
#pragma unroll
        for (int k = 0; k < 6; ++k) {
            const float g = (float)(base + k);
            pbuf[42 + pw * 6 + k] = hat_int(xb, g) - hat_int(xa, g);
        }
    } else if (tid == PH + PW) {                  // inv_area
        const float roi_w = fmaxf(x2 - x1, 0.0f);
        const float roi_h = fmaxf(y2 - y1, 0.0f);
        const float area = (roi_w / (float)PW) * (roi_h / (float)PH);
        pbuf[98] = (area > 0.0f) ? (1.0f / area) : 0.0f;
    }
    __syncthreads();

    // ---- PA: rs[pw][j][c8] = sum_i wx * patch ----
    const int nA = JROWS * 14;
    {
        const int v1 = tid;
        if (v1 < nA) {
            const int j = v1 / 14; const int rem = v1 - j * 14;
            const int pw = rem >> 1, q = rem & 1;
            const int bi = __float_as_int(pbuf[91 + pw]);
            const float* base = &patch[((size_t)j * ROWF + bi) * CB + 4 * q];
            float ax = 0.0f, ay = 0.0f, az = 0.0f, aw = 0.0f;
#pragma unroll
            for (int ii = 0; ii < 6; ++ii) {
                const float w = pbuf[42 + pw * 6 + ii];
                const float4 v = *(const float4*)(base + ii * CB);
                ax += w * v.x; ay += w * v.y; az += w * v.z; aw += w * v.w;
            }
            *(float4*)(&rs[((size_t)pw * MAXJ + j) * CB + 4 * q]) =
                make_float4(ax, ay, az, aw);
        }
        const int v2 = tid + 256;
        if (v2 < nA) {                            // only when JROWS >= 19
            const int j = v2 / 14; const int rem = v2 - j * 14;
            const int pw = rem >> 1, q = rem & 1;
            const int bi = __float_as_int(pbuf[91 + pw]);
            const float* base = &patch[((size_t)j * ROWF + bi) * CB + 4 * q];
            float ax = 0.0f, ay = 0.0f, az = 0.0f, aw = 0.0f;
#pragma unroll
            for (int ii = 0; ii < 6; ++ii) {
                const float w = pbuf[42 + pw * 6 + ii];
                const float4 v = *(const float4*)(base + ii * CB);
                ax += w * v.x; ay += w * v.y; az += w * v.z; aw += w * v.w;
            }
            *(float4*)(&rs[((size_t)pw * MAXJ + j) * CB + 4 * q]) =
                make_float4(ax, ay, az, aw);
        }
    }
    __syncthreads();

    // ---- PB: combine over rows, float2 channel-pairs ----
    const int bin = tid & 63;
    const int cp  = tid >> 6;
    if (bin < NBINS) {
        const int phv = bin / PW, pwv = bin - phv * PW;
        const int bj = __float_as_int(pbuf[84 + phv]);
        const float inv_area = pbuf[98];
        const float* rbase = &rs[((size_t)pwv * MAXJ + bj) * CB + 2 * cp];
        float ax = 0.0f, ay = 0.0f;
#pragma unroll
        for (int jj = 0; jj < 6; ++jj) {
            const float w = pbuf[phv * 6 + jj];
            const float2 v = *(const float2*)(rbase + jj * CB);
            ax += w * v.x; ay += w * v.y;
        }
        float* o = out + ((size_t)r * CH + c0 + 2 * cp) * NBINS + bin;
        o[0]     = ax * inv_area;
        o[NBINS] = ay * inv_area;
    }
}

extern "C" void kernel_launch(void* const* d_in, const int* in_sizes, int n_in,
                              void* d_out, int out_size, void* d_ws, size_t ws_size,
                              hipStream_t stream) {
    const float* feat = (const float*)d_in[0];
    const float* rois = (const float*)d_in[1];
    float* out = (float*)d_out;
    (void)d_ws; (void)ws_size;   // workspace-free: avoid the 256 MiB re-poison

    prroi_fused<<<dim3(CH / CB, RNUM), 256, 0, stream>>>(feat, rois, out);
}